// Round 4
// baseline (154.102 us; speedup 1.0000x reference)
//
#include <hip/hip_runtime.h>
#include <hip/hip_bf16.h>

typedef float    f32x4 __attribute__((ext_vector_type(4)));
typedef _Float16 f16x8 __attribute__((ext_vector_type(8)));
typedef __fp16   fp16x2 __attribute__((ext_vector_type(2)));

#define NN 4096
#define INF_ 256
#define OUTF 64
#define NH 4
#define LOG2E 1.4426950408889634f
#define NSPLIT 4
#define JRANGE (NN / NSPLIT)      // 1024
#define STEPS (JRANGE / 32)       // 32

__device__ __forceinline__ unsigned enc_f32(float f) {
    unsigned u = __float_as_uint(f);
    return (u & 0x80000000u) ? ~u : (u | 0x80000000u);
}
__device__ __forceinline__ float dec_f32(unsigned u) {
    return (u & 0x80000000u) ? __uint_as_float(u ^ 0x80000000u)
                             : __uint_as_float(~u);
}

// ---------------------------------------------------------------------------
// K0: pack adj (0/1 floats) into a bitmask, diagonal forced to 1.
// One wave per row; coalesced f32 loads + __ballot -> 2 u32 stores / 64 j.
// ---------------------------------------------------------------------------
__global__ __launch_bounds__(256) void k0_pack(const float* __restrict__ adj,
                                               unsigned* __restrict__ pack)
{
    const int r    = (blockIdx.x << 2) + (threadIdx.x >> 6);  // row = wave id
    const int lane = threadIdx.x & 63;
    const float* row = adj + (size_t)r * NN;
    for (int jb = 0; jb < NN; jb += 64) {
        float v = row[jb + lane];
        unsigned long long bal = __ballot(v != 0.0f);
        if (lane < 2) {
            unsigned word = (unsigned)(bal >> (lane * 32));
            int wi = (jb >> 5) + lane;
            if (wi == (r >> 5)) word |= (1u << (r & 31));   // diagonal -> 1
            pack[r * 128 + wi] = word;
        }
    }
}

// ---------------------------------------------------------------------------
// K1: Wh = x @ W (f32 acc), whT[h][o][n] f16; s_src/s_dst = log2e*(Wh.a);
//     smax[h] upper bound via encoded-u32 atomicMax.
// ---------------------------------------------------------------------------
__global__ __launch_bounds__(256) void k1_wh(
    const float* __restrict__ x, const float* __restrict__ W,
    const float* __restrict__ a, _Float16* __restrict__ whT,
    float* __restrict__ s_src, float* __restrict__ s_dst,
    unsigned* __restrict__ smax)
{
    const int n0 = blockIdx.x * 8;
    const int t = threadIdx.x;
    const int h = t >> 6, o = t & 63, lane = t & 63;

    float acc[8] = {0.f,0.f,0.f,0.f,0.f,0.f,0.f,0.f};
    const float* wp = W + h * INF_ * OUTF + o;

    for (int d = 0; d < INF_; d += 4) {
        float w0 = wp[(d+0)*OUTF];
        float w1 = wp[(d+1)*OUTF];
        float w2 = wp[(d+2)*OUTF];
        float w3 = wp[(d+3)*OUTF];
#pragma unroll
        for (int nn = 0; nn < 8; ++nn) {
            float4 xv = *reinterpret_cast<const float4*>(x + (n0+nn)*INF_ + d);
            acc[nn] += xv.x*w0 + xv.y*w1 + xv.z*w2 + xv.w*w3;
        }
    }

    f16x8 hv;
#pragma unroll
    for (int nn = 0; nn < 8; ++nn) hv[nn] = (_Float16)acc[nn];
    *reinterpret_cast<f16x8*>(whT + (h*OUTF + o)*NN + n0) = hv;

    const float asrc = a[h*128 + o];
    const float adst = a[h*128 + 64 + o];
    float vmax = -3.0e38f;
#pragma unroll
    for (int nn = 0; nn < 8; ++nn) {
        float vs = acc[nn] * asrc;
        float vd = acc[nn] * adst;
#pragma unroll
        for (int m = 1; m <= 32; m <<= 1) {
            vs += __shfl_xor(vs, m);
            vd += __shfl_xor(vd, m);
        }
        if (lane == 0) {
            s_src[h*NN + n0 + nn] = LOG2E * vs;
            s_dst[h*NN + n0 + nn] = LOG2E * vd;
            vmax = fmaxf(vmax, LOG2E * vd);
        }
    }
    if (lane == 0) atomicMax(&smax[h], enc_f32(vmax));
}

// ---------------------------------------------------------------------------
// K3: barrier-free fused softmax + P@Wh.
// Grid 1024 x 256: block b -> jsplit=b&3, head=(b>>2)&3, row-group=b>>4.
// Wave w owns 16 i-rows; streams 32-j steps: bitmask dword + s_dst + 4
// whT B-frags straight from L2; P built in-register in A-frag layout.
// Per-row fixed bound m = LR(s_i + smax) => p=exp2(..)<=1, partials addable.
// ---------------------------------------------------------------------------
template <int USE_PART>
__global__ __launch_bounds__(256) void k3_attn(
    const unsigned* __restrict__ pack, const _Float16* __restrict__ whT,
    const float* __restrict__ s_src, const float* __restrict__ s_dst,
    const unsigned* __restrict__ smax_enc,
    float* __restrict__ outp, float* __restrict__ l_ws)
{
    const int b      = blockIdx.x;
    const int jsplit = b & (NSPLIT - 1);
    const int h      = (b >> 2) & 3;
    const int grp    = b >> 4;
    const int w      = threadIdx.x >> 6;
    const int lane   = threadIdx.x & 63;
    const int row16  = lane & 15;
    const int quad   = lane >> 4;
    const int i0     = (grp * 4 + w) * 16;
    const int i_row  = i0 + row16;

    const float s_i = s_src[h*NN + i_row];
    const float sm  = dec_f32(smax_enc[h]);
    const float zb  = s_i + sm;
    const float mb  = fmaxf(zb, 0.2f * zb);
    const float A1  = s_i - mb;
    const float A2  = 0.2f * s_i - mb;

    f32x4 acc0 = {0,0,0,0}, acc1 = {0,0,0,0}, acc2 = {0,0,0,0}, acc3 = {0,0,0,0};
    float lsum = 0.f;

    const int jb0 = jsplit * JRANGE;
    const unsigned* prow = pack + i_row*128 + (jb0 >> 5);
    const float*    sdp  = s_dst + h*NN + jb0 + quad*8;
    const _Float16* bb   = whT + (size_t)(h*OUTF + row16)*NN + jb0 + quad*8;

#pragma unroll 2
    for (int s = 0; s < STEPS; ++s) {
        const unsigned m32 = prow[s];
        const unsigned mm8 = (m32 >> (quad * 8)) & 0xffu;
        const float4 sj0 = *reinterpret_cast<const float4*>(sdp + s*32);
        const float4 sj1 = *reinterpret_cast<const float4*>(sdp + s*32 + 4);
        const f16x8 b0 = *reinterpret_cast<const f16x8*>(bb + s*32);
        const f16x8 b1 = *reinterpret_cast<const f16x8*>(bb + 16*NN + s*32);
        const f16x8 b2 = *reinterpret_cast<const f16x8*>(bb + 32*NN + s*32);
        const f16x8 b3 = *reinterpret_cast<const f16x8*>(bb + 48*NN + s*32);

        const float sjv[8] = {sj0.x,sj0.y,sj0.z,sj0.w,sj1.x,sj1.y,sj1.z,sj1.w};
        float pe[8];
#pragma unroll
        for (int e = 0; e < 8; ++e) {
            float sj = sjv[e];
            float t1 = A1 + sj;
            float t2 = __builtin_fmaf(0.2f, sj, A2);
            float el = fmaxf(t1, t2);
            float p  = __builtin_amdgcn_exp2f(el);
            p = (mm8 & (1u << e)) ? p : 0.0f;
            lsum += p;
            pe[e] = p;
        }
        union { f16x8 v8; fp16x2 p2[4]; } pa;
#pragma unroll
        for (int e2 = 0; e2 < 4; ++e2)
            pa.p2[e2] = __builtin_amdgcn_cvt_pkrtz(pe[2*e2], pe[2*e2+1]);

        acc0 = __builtin_amdgcn_mfma_f32_16x16x32_f16(pa.v8, b0, acc0, 0, 0, 0);
        acc1 = __builtin_amdgcn_mfma_f32_16x16x32_f16(pa.v8, b1, acc1, 0, 0, 0);
        acc2 = __builtin_amdgcn_mfma_f32_16x16x32_f16(pa.v8, b2, acc2, 0, 0, 0);
        acc3 = __builtin_amdgcn_mfma_f32_16x16x32_f16(pa.v8, b3, acc3, 0, 0, 0);
    }

    // row-sum l: reduce over the 4 quads
    lsum += __shfl_xor(lsum, 16);
    lsum += __shfl_xor(lsum, 32);
    if (USE_PART) {
        if (lane < 16) l_ws[(jsplit*NH + h)*NN + i_row] = lsum;
    } else {
        if (lane < 16) atomicAdd(&l_ws[h*NN + i_row], lsum);
    }

    const f32x4 av[4] = {acc0, acc1, acc2, acc3};
#pragma unroll
    for (int ob = 0; ob < 4; ++ob) {
#pragma unroll
        for (int q = 0; q < 4; ++q) {
            const int grow = i0 + quad*4 + q;            // C/D: row=(lane>>4)*4+reg
            const int gcol = h*OUTF + ob*16 + row16;     // C/D: col=lane&15
            if (USE_PART)
                outp[((size_t)(jsplit*NN + grow))*256 + gcol] = av[ob][q];
            else
                atomicAdd(&outp[(size_t)grow*256 + gcol], av[ob][q]);
        }
    }
}

// ---------------------------------------------------------------------------
// K4 (partials path): out = (sum_sp part_sp) / (sum_sp l_sp)
// ---------------------------------------------------------------------------
__global__ __launch_bounds__(256) void k4_part(const float* __restrict__ part,
                                               const float* __restrict__ l_ws,
                                               float* __restrict__ out)
{
    const int idx = blockIdx.x * 256 + threadIdx.x;   // f32x4 index, < 262144
    const int n = idx >> 6, c4 = idx & 63, h = c4 >> 4;
    float L = 0.f;
    f32x4 v = {0,0,0,0};
#pragma unroll
    for (int sp = 0; sp < NSPLIT; ++sp) {
        L += l_ws[(sp*NH + h)*NN + n];
        v += *reinterpret_cast<const f32x4*>(part + ((size_t)(sp*NN + n))*256 + c4*4);
    }
    const float inv = 1.0f / L;
    *reinterpret_cast<f32x4*>(out + (size_t)n*256 + c4*4) = v * inv;
}

// K4 (atomic fallback): out /= l
__global__ __launch_bounds__(256) void k4_atomic(float* __restrict__ out,
                                                 const float* __restrict__ l_acc)
{
    const int idx = blockIdx.x * 256 + threadIdx.x;
    const int n = idx >> 6, c4 = idx & 63, h = c4 >> 4;
    const float inv = 1.0f / l_acc[h*NN + n];
    f32x4 v = *reinterpret_cast<f32x4*>(out + (size_t)n*256 + c4*4);
    *reinterpret_cast<f32x4*>(out + (size_t)n*256 + c4*4) = v * inv;
}

extern "C" void kernel_launch(void* const* d_in, const int* in_sizes, int n_in,
                              void* d_out, int out_size, void* d_ws, size_t ws_size,
                              hipStream_t stream)
{
    const float* x   = (const float*)d_in[0];
    const float* adj = (const float*)d_in[1];
    const float* W   = (const float*)d_in[2];
    const float* a   = (const float*)d_in[3];
    float* out = (float*)d_out;

    char* ws = (char*)d_ws;
    _Float16* whT  = (_Float16*)ws;                         // 2 MB
    unsigned* pack = (unsigned*)(ws + (2u<<20));            // 2 MB
    float* s_src   = (float*)(ws + (4u<<20));               // 64 KB
    float* s_dst   = (float*)(ws + (4u<<20) + (64u<<10));   // 64 KB
    unsigned* smax = (unsigned*)(ws + (4u<<20) + (128u<<10)); // 256 B
    float* l_ws    = (float*)(ws + (4u<<20) + (128u<<10) + 256); // <=256 KB
    float* part    = (float*)(ws + (4u<<20) + (384u<<10) + 256); // 16 MB

    const size_t need_part = (4u<<20) + (384u<<10) + 256 + (16u<<20);
    const int use_part = (ws_size >= need_part);

    (void)hipMemsetAsync(smax, 0, 16, stream);
    if (!use_part) {
        (void)hipMemsetAsync(d_out, 0, (size_t)out_size * sizeof(float), stream);
        (void)hipMemsetAsync(l_ws, 0, NH * NN * sizeof(float), stream);
    }

    k0_pack<<<NN/4, 256, 0, stream>>>(adj, pack);
    k1_wh  <<<NN/8, 256, 0, stream>>>(x, W, a, whT, s_src, s_dst, smax);
    if (use_part) {
        k3_attn<1><<<1024, 256, 0, stream>>>(pack, whT, s_src, s_dst, smax, part, l_ws);
        k4_part<<<1024, 256, 0, stream>>>(part, l_ws, out);
    } else {
        k3_attn<0><<<1024, 256, 0, stream>>>(pack, whT, s_src, s_dst, smax, out, l_ws);
        k4_atomic<<<1024, 256, 0, stream>>>(out, l_ws);
    }
}

// Round 6
// 118.811 us; speedup vs baseline: 1.2970x; 1.2970x over previous
//
#include <hip/hip_runtime.h>
#include <hip/hip_bf16.h>

typedef float    f32x4 __attribute__((ext_vector_type(4)));
typedef _Float16 f16x8 __attribute__((ext_vector_type(8)));
typedef __fp16   fp16x2 __attribute__((ext_vector_type(2)));

#define NN 4096
#define INF_ 256
#define OUTF 64
#define NH 4
#define LOG2E 1.4426950408889634f

// ---------------------------------------------------------------------------
// K0: pack adj (0/1 floats) into bitmask; diagonal forced 1; init smax.
// One block per row; 4 waves; 4 loads in flight per wave (latency hiding).
// ---------------------------------------------------------------------------
__global__ __launch_bounds__(256) void k0_pack(const float* __restrict__ adj,
                                               unsigned* __restrict__ pack,
                                               unsigned* __restrict__ smax)
{
    const int r    = blockIdx.x;
    const int w    = threadIdx.x >> 6;
    const int lane = threadIdx.x & 63;
    const float* row = adj + (size_t)r * NN + w * 1024;
#pragma unroll
    for (int i = 0; i < 4; ++i) {
        float a0 = row[i*256 + lane];
        float a1 = row[i*256 +  64 + lane];
        float a2 = row[i*256 + 128 + lane];
        float a3 = row[i*256 + 192 + lane];
        unsigned long long bal[4];
        bal[0] = __ballot(a0 != 0.f);
        bal[1] = __ballot(a1 != 0.f);
        bal[2] = __ballot(a2 != 0.f);
        bal[3] = __ballot(a3 != 0.f);
        if (lane < 2) {
#pragma unroll
            for (int k = 0; k < 4; ++k) {
                int wi = w*32 + i*8 + k*2 + lane;
                unsigned v = (unsigned)(bal[k] >> (lane * 32));
                if (wi == (r >> 5)) v |= 1u << (r & 31);   // diagonal
                pack[r*128 + wi] = v;
            }
        }
    }
    if (r == 0 && threadIdx.x < NH) smax[threadIdx.x] = 0u;
}

__device__ __forceinline__ unsigned enc_f32(float f) {
    unsigned u = __float_as_uint(f);
    return (u & 0x80000000u) ? ~u : (u | 0x80000000u);
}
__device__ __forceinline__ float dec_f32(unsigned u) {
    return (u & 0x80000000u) ? __uint_as_float(u ^ 0x80000000u)
                             : __uint_as_float(~u);
}

// ---------------------------------------------------------------------------
// K1: Wh = x @ W (f32 acc), whT[h][o][n] f16; s_src/s_dst = log2e*(Wh.a);
//     smax[h] upper bound via encoded-u32 atomicMax.
// ---------------------------------------------------------------------------
__global__ __launch_bounds__(256) void k1_wh(
    const float* __restrict__ x, const float* __restrict__ W,
    const float* __restrict__ a, _Float16* __restrict__ whT,
    float* __restrict__ s_src, float* __restrict__ s_dst,
    unsigned* __restrict__ smax)
{
    const int n0 = blockIdx.x * 8;
    const int t = threadIdx.x;
    const int h = t >> 6, o = t & 63, lane = t & 63;

    float acc[8] = {0.f,0.f,0.f,0.f,0.f,0.f,0.f,0.f};
    const float* wp = W + h * INF_ * OUTF + o;

    for (int d = 0; d < INF_; d += 4) {
        float w0 = wp[(d+0)*OUTF];
        float w1 = wp[(d+1)*OUTF];
        float w2 = wp[(d+2)*OUTF];
        float w3 = wp[(d+3)*OUTF];
#pragma unroll
        for (int nn = 0; nn < 8; ++nn) {
            float4 xv = *reinterpret_cast<const float4*>(x + (n0+nn)*INF_ + d);
            acc[nn] += xv.x*w0 + xv.y*w1 + xv.z*w2 + xv.w*w3;
        }
    }

    f16x8 hv;
#pragma unroll
    for (int nn = 0; nn < 8; ++nn) hv[nn] = (_Float16)acc[nn];
    *reinterpret_cast<f16x8*>(whT + (h*OUTF + o)*NN + n0) = hv;

    const float asrc = a[h*128 + o];
    const float adst = a[h*128 + 64 + o];
    float vmax = -3.0e38f;
#pragma unroll
    for (int nn = 0; nn < 8; ++nn) {
        float vs = acc[nn] * asrc;
        float vd = acc[nn] * adst;
#pragma unroll
        for (int m = 1; m <= 32; m <<= 1) {
            vs += __shfl_xor(vs, m);
            vd += __shfl_xor(vd, m);
        }
        if (lane == 0) {
            s_src[h*NN + n0 + nn] = LOG2E * vs;
            s_dst[h*NN + n0 + nn] = LOG2E * vd;
            vmax = fmaxf(vmax, LOG2E * vd);
        }
    }
    if (lane == 0) atomicMax(&smax[h], enc_f32(vmax));
}

// ---------------------------------------------------------------------------
// K3: barrier-free fused softmax + P@Wh.
// Wave owns ROWS i-rows (NF=ROWS/16 A-frags sharing B-frags), streams 32-j
// steps with 1-step register prefetch of B-frags+masks. Ones-column MFMA
// accumulates the softmax denominator in the matrix pipe.
// Per-row fixed bound m = LR(s_i + smax) => p = exp2(..) <= 1.
// ---------------------------------------------------------------------------
template <int ROWS, int NSPL, int USE_PART>
__global__ __launch_bounds__(256, 4) void k3_attn(
    const unsigned* __restrict__ pack, const _Float16* __restrict__ whT,
    const float* __restrict__ s_src, const float* __restrict__ s_dst,
    const unsigned* __restrict__ smax_enc,
    float* __restrict__ outp, float* __restrict__ l_ws)
{
    constexpr int NF = ROWS / 16;
    constexpr int STEPS_ = NN / NSPL / 32;

    const int b      = blockIdx.x;
    const int jsplit = b % NSPL;
    const int r2     = b / NSPL;
    const int hh     = r2 & 3;
    const int grp    = r2 >> 2;
    const int w      = threadIdx.x >> 6;
    const int lane   = threadIdx.x & 63;
    const int row16  = lane & 15;
    const int quad   = lane >> 4;
    const int i0     = (grp * 4 + w) * ROWS;
    const int jb0    = jsplit * (NN / NSPL);

    const float sm = dec_f32(smax_enc[hh]);
    float A1[NF], A2[NF];
    const unsigned* prow[NF];
#pragma unroll
    for (int f = 0; f < NF; ++f) {
        const int ir = i0 + f*16 + row16;
        const float s_i = s_src[hh*NN + ir];
        const float zb  = s_i + sm;
        const float mb  = fmaxf(zb, 0.2f * zb);
        A1[f] = s_i - mb;
        A2[f] = 0.2f * s_i - mb;
        prow[f] = pack + ir*128 + (jb0 >> 5);
    }

    f32x4 acc[NF][4];
    f32x4 accl[NF];
#pragma unroll
    for (int f = 0; f < NF; ++f) {
        accl[f] = (f32x4){0,0,0,0};
#pragma unroll
        for (int ob = 0; ob < 4; ++ob) acc[f][ob] = (f32x4){0,0,0,0};
    }

    f16x8 ones;
#pragma unroll
    for (int e = 0; e < 8; ++e) ones[e] = (_Float16)1.0f;

    const float*    sdp  = s_dst + hh*NN + jb0 + quad*8;
    const _Float16* bptr = whT + (size_t)(hh*OUTF + row16)*NN + jb0 + quad*8;

    // prologue: load step-0 B-frags + masks
    f16x8 B0 = *reinterpret_cast<const f16x8*>(bptr);
    f16x8 B1 = *reinterpret_cast<const f16x8*>(bptr + 16*NN);
    f16x8 B2 = *reinterpret_cast<const f16x8*>(bptr + 32*NN);
    f16x8 B3 = *reinterpret_cast<const f16x8*>(bptr + 48*NN);
    unsigned msk[NF];
#pragma unroll
    for (int f = 0; f < NF; ++f) msk[f] = prow[f][0];

    for (int s = 0; s < STEPS_; ++s) {
        // ---- prefetch step s+1 (1-step overread lands in ws, harmless) ----
        const _Float16* bn = bptr + (s+1)*32;
        f16x8 nB0 = *reinterpret_cast<const f16x8*>(bn);
        f16x8 nB1 = *reinterpret_cast<const f16x8*>(bn + 16*NN);
        f16x8 nB2 = *reinterpret_cast<const f16x8*>(bn + 32*NN);
        f16x8 nB3 = *reinterpret_cast<const f16x8*>(bn + 48*NN);
        unsigned nmsk[NF];
#pragma unroll
        for (int f = 0; f < NF; ++f) nmsk[f] = prow[f][s+1];

        // ---- s_dst (16 lanes share each address -> L1 broadcast) ----
        const float4 sj0 = *reinterpret_cast<const float4*>(sdp + s*32);
        const float4 sj1 = *reinterpret_cast<const float4*>(sdp + s*32 + 4);
        const float sjv[8] = {sj0.x,sj0.y,sj0.z,sj0.w,sj1.x,sj1.y,sj1.z,sj1.w};
        float us[8];
#pragma unroll
        for (int e = 0; e < 8; ++e) us[e] = 0.2f * sjv[e];

#pragma unroll
        for (int f = 0; f < NF; ++f) {
            const unsigned mm8 = (msk[f] >> (quad * 8)) & 0xffu;
            float pe[8];
#pragma unroll
            for (int e = 0; e < 8; ++e) {
                float t1 = A1[f] + sjv[e];
                float t2 = A2[f] + us[e];
                float p  = __builtin_amdgcn_exp2f(fmaxf(t1, t2));
                pe[e] = (mm8 & (1u << e)) ? p : 0.0f;
            }
            union { f16x8 v8; fp16x2 p2[4]; } pa;
#pragma unroll
            for (int e2 = 0; e2 < 4; ++e2)
                pa.p2[e2] = __builtin_amdgcn_cvt_pkrtz(pe[2*e2], pe[2*e2+1]);

            acc[f][0] = __builtin_amdgcn_mfma_f32_16x16x32_f16(pa.v8, B0, acc[f][0], 0, 0, 0);
            acc[f][1] = __builtin_amdgcn_mfma_f32_16x16x32_f16(pa.v8, B1, acc[f][1], 0, 0, 0);
            acc[f][2] = __builtin_amdgcn_mfma_f32_16x16x32_f16(pa.v8, B2, acc[f][2], 0, 0, 0);
            acc[f][3] = __builtin_amdgcn_mfma_f32_16x16x32_f16(pa.v8, B3, acc[f][3], 0, 0, 0);
            accl[f]   = __builtin_amdgcn_mfma_f32_16x16x32_f16(pa.v8, ones, accl[f], 0, 0, 0);
        }

        B0 = nB0; B1 = nB1; B2 = nB2; B3 = nB3;
#pragma unroll
        for (int f = 0; f < NF; ++f) msk[f] = nmsk[f];
    }

    // ---- epilogue ----
#pragma unroll
    for (int f = 0; f < NF; ++f) {
        if (row16 == 0) {   // accl[f][q] = rowsum(P) for row i0+f*16+quad*4+q
#pragma unroll
            for (int q = 0; q < 4; ++q) {
                const int ir = i0 + f*16 + quad*4 + q;
                if (USE_PART) l_ws[(jsplit*NH + hh)*NN + ir] = accl[f][q];
                else          atomicAdd(&l_ws[hh*NN + ir], accl[f][q]);
            }
        }
#pragma unroll
        for (int ob = 0; ob < 4; ++ob) {
#pragma unroll
            for (int q = 0; q < 4; ++q) {
                const int grow = i0 + f*16 + quad*4 + q;   // C/D: row=(lane>>4)*4+reg
                const int gcol = hh*OUTF + ob*16 + row16;  // C/D: col=lane&15
                if (USE_PART)
                    outp[((size_t)(jsplit*NN + grow))*256 + gcol] = acc[f][ob][q];
                else
                    atomicAdd(&outp[(size_t)grow*256 + gcol], acc[f][ob][q]);
            }
        }
    }
}

// ---------------------------------------------------------------------------
// K4 (partials): out = (sum_sp part_sp) / (sum_sp l_sp)
// ---------------------------------------------------------------------------
template <int NSPL>
__global__ __launch_bounds__(256) void k4_part(const float* __restrict__ part,
                                               const float* __restrict__ l_ws,
                                               float* __restrict__ out)
{
    const int idx = blockIdx.x * 256 + threadIdx.x;   // f32x4 index, < 262144
    const int n = idx >> 6, c4 = idx & 63, h = c4 >> 4;
    float L = 0.f;
    f32x4 v = {0,0,0,0};
#pragma unroll
    for (int sp = 0; sp < NSPL; ++sp) {
        L += l_ws[(sp*NH + h)*NN + n];
        v += *reinterpret_cast<const f32x4*>(part + ((size_t)(sp*NN + n))*256 + c4*4);
    }
    const float inv = 1.0f / L;
    *reinterpret_cast<f32x4*>(out + (size_t)n*256 + c4*4) = v * inv;
}

// K4 (atomic fallback): out /= l
__global__ __launch_bounds__(256) void k4_atomic(float* __restrict__ out,
                                                 const float* __restrict__ l_acc)
{
    const int idx = blockIdx.x * 256 + threadIdx.x;
    const int n = idx >> 6, c4 = idx & 63, h = c4 >> 4;
    const float inv = 1.0f / l_acc[h*NN + n];
    f32x4 v = *reinterpret_cast<f32x4*>(out + (size_t)n*256 + c4*4);
    *reinterpret_cast<f32x4*>(out + (size_t)n*256 + c4*4) = v * inv;
}

extern "C" void kernel_launch(void* const* d_in, const int* in_sizes, int n_in,
                              void* d_out, int out_size, void* d_ws, size_t ws_size,
                              hipStream_t stream)
{
    const float* x   = (const float*)d_in[0];
    const float* adj = (const float*)d_in[1];
    const float* W   = (const float*)d_in[2];
    const float* a   = (const float*)d_in[3];
    float* out = (float*)d_out;

    char* ws = (char*)d_ws;
    _Float16* whT  = (_Float16*)ws;                              // 2 MB
    unsigned* pack = (unsigned*)(ws + (2u<<20));                 // 2 MB
    float* s_src   = (float*)(ws + (4u<<20));                    // 64 KB
    float* s_dst   = (float*)(ws + (4u<<20) + (64u<<10));        // 64 KB
    unsigned* smax = (unsigned*)(ws + (4u<<20) + (128u<<10));    // 1 KB slot
    float* l_ws    = (float*)(ws + (4u<<20) + (129u<<10));       // <=512 KB
    float* part    = (float*)(ws + (4u<<20) + (641u<<10));       // NSPL*4 MB

    const size_t base   = (4u<<20) + (641u<<10);
    const size_t need8  = base + (size_t)8 * NN * 256 * 4;       // ~36.6 MB
    const size_t need4  = base + (size_t)4 * NN * 256 * 4;       // ~20.6 MB

    k0_pack<<<NN, 256, 0, stream>>>(adj, pack, smax);
    k1_wh  <<<NN/8, 256, 0, stream>>>(x, W, a, whT, s_src, s_dst, smax);

    if (ws_size >= need8) {
        k3_attn<32, 8, 1><<<1024, 256, 0, stream>>>(pack, whT, s_src, s_dst, smax, part, l_ws);
        k4_part<8><<<1024, 256, 0, stream>>>(part, l_ws, out);
    } else if (ws_size >= need4) {
        k3_attn<16, 4, 1><<<1024, 256, 0, stream>>>(pack, whT, s_src, s_dst, smax, part, l_ws);
        k4_part<4><<<1024, 256, 0, stream>>>(part, l_ws, out);
    } else {
        (void)hipMemsetAsync(d_out, 0, (size_t)out_size * sizeof(float), stream);
        (void)hipMemsetAsync(l_ws, 0, NH * NN * sizeof(float), stream);
        k3_attn<16, 4, 0><<<1024, 256, 0, stream>>>(pack, whT, s_src, s_dst, smax, out, l_ws);
        k4_atomic<<<1024, 256, 0, stream>>>(out, l_ws);
    }
}

// Round 7
// 97.753 us; speedup vs baseline: 1.5764x; 1.2154x over previous
//
#include <hip/hip_runtime.h>
#include <hip/hip_bf16.h>

typedef float    f32x4 __attribute__((ext_vector_type(4)));
typedef _Float16 f16x8 __attribute__((ext_vector_type(8)));
typedef __fp16   fp16x2 __attribute__((ext_vector_type(2)));

#define NN 4096
#define INF_ 256
#define OUTF 64
#define NH 4
#define NSPL 8
#define NGRP 128            // NN/32
#define LOG2E 1.4426950408889634f

// ---------------------------------------------------------------------------
// K0: pack adj (0/1 floats) into bitmask; diagonal forced 1; init smax.
// ---------------------------------------------------------------------------
__global__ __launch_bounds__(256) void k0_pack(const float* __restrict__ adj,
                                               unsigned* __restrict__ pack,
                                               unsigned* __restrict__ smax)
{
    const int r    = blockIdx.x;
    const int w    = threadIdx.x >> 6;
    const int lane = threadIdx.x & 63;
    const float* row = adj + (size_t)r * NN + w * 1024;
#pragma unroll
    for (int i = 0; i < 4; ++i) {
        float a0 = row[i*256 + lane];
        float a1 = row[i*256 +  64 + lane];
        float a2 = row[i*256 + 128 + lane];
        float a3 = row[i*256 + 192 + lane];
        unsigned long long bal[4];
        bal[0] = __ballot(a0 != 0.f);
        bal[1] = __ballot(a1 != 0.f);
        bal[2] = __ballot(a2 != 0.f);
        bal[3] = __ballot(a3 != 0.f);
        if (lane < 2) {
#pragma unroll
            for (int k = 0; k < 4; ++k) {
                int wi = w*32 + i*8 + k*2 + lane;
                unsigned v = (unsigned)(bal[k] >> (lane * 32));
                if (wi == (r >> 5)) v |= 1u << (r & 31);   // diagonal
                pack[r*128 + wi] = v;
            }
        }
    }
    if (r == 0 && threadIdx.x < NH) smax[threadIdx.x] = 0u;
}

__device__ __forceinline__ unsigned enc_f32(float f) {
    unsigned u = __float_as_uint(f);
    return (u & 0x80000000u) ? ~u : (u | 0x80000000u);
}
__device__ __forceinline__ float dec_f32(unsigned u) {
    return (u & 0x80000000u) ? __uint_as_float(u ^ 0x80000000u)
                             : __uint_as_float(~u);
}

// ---------------------------------------------------------------------------
// K1: Wh = x @ W. x staged in LDS (8 rows, broadcast reads). Writes Wh in
// MFMA-B fragment-native order: whB[h][jblk][ob][lane][e] (16B/thread store).
// Also s_src/s_dst = log2e*(Wh.a) and smax via encoded atomicMax.
// ---------------------------------------------------------------------------
__global__ __launch_bounds__(256) void k1_wh(
    const float* __restrict__ x, const float* __restrict__ W,
    const float* __restrict__ a, _Float16* __restrict__ whB,
    float* __restrict__ s_src, float* __restrict__ s_dst,
    unsigned* __restrict__ smax)
{
    __shared__ float xs[8][256];
    const int n0 = blockIdx.x * 8;
    const int t = threadIdx.x;
    {
        const int row = t >> 5, c8 = (t & 31) * 8;
        float4 v0 = *reinterpret_cast<const float4*>(x + (n0+row)*INF_ + c8);
        float4 v1 = *reinterpret_cast<const float4*>(x + (n0+row)*INF_ + c8 + 4);
        *reinterpret_cast<float4*>(&xs[row][c8])   = v0;
        *reinterpret_cast<float4*>(&xs[row][c8+4]) = v1;
    }
    __syncthreads();

    const int h = t >> 6, o = t & 63, lane = t & 63;
    float acc[8] = {0.f,0.f,0.f,0.f,0.f,0.f,0.f,0.f};
    const float* wp = W + h * INF_ * OUTF + o;

    for (int d = 0; d < INF_; d += 4) {
        float w0 = wp[(d+0)*OUTF];
        float w1 = wp[(d+1)*OUTF];
        float w2 = wp[(d+2)*OUTF];
        float w3 = wp[(d+3)*OUTF];
#pragma unroll
        for (int nn = 0; nn < 8; ++nn) {
            float4 xv = *reinterpret_cast<const float4*>(&xs[nn][d]);  // broadcast
            acc[nn] += xv.x*w0 + xv.y*w1 + xv.z*w2 + xv.w*w3;
        }
    }

    // fragment-native store: whB[h][jblk][ob=o>>4][lane=quad*16+(o&15)][e=0..7]
    f16x8 hv;
#pragma unroll
    for (int nn = 0; nn < 8; ++nn) hv[nn] = (_Float16)acc[nn];
    const int jblk = n0 >> 5, quad = (n0 >> 3) & 3;
    const size_t off = ((((size_t)(h*NGRP + jblk)*4) + (o>>4))*64 + quad*16 + (o&15))*8;
    *reinterpret_cast<f16x8*>(whB + off) = hv;

    const float asrc = a[h*128 + o];
    const float adst = a[h*128 + 64 + o];
    float vmax = -3.0e38f;
#pragma unroll
    for (int nn = 0; nn < 8; ++nn) {
        float vs = acc[nn] * asrc;
        float vd = acc[nn] * adst;
#pragma unroll
        for (int m = 1; m <= 32; m <<= 1) {
            vs += __shfl_xor(vs, m);
            vd += __shfl_xor(vd, m);
        }
        if (lane == 0) {
            s_src[h*NN + n0 + nn] = LOG2E * vs;
            s_dst[h*NN + n0 + nn] = LOG2E * vd;
            vmax = fmaxf(vmax, LOG2E * vd);
        }
    }
    if (lane == 0) atomicMax(&smax[h], enc_f32(vmax));
}

// ---------------------------------------------------------------------------
// K3: barrier-free fused softmax + P@Wh. Wave owns 32 i-rows (2 A-frags
// share B-frags). B-frags stream from fragment-native whB (1KB contiguous
// per load). Full 1-step register prefetch (B, masks, s_dst). Ones-column
// MFMA accumulates the denominator. Partials stored wave-native (coalesced).
// ---------------------------------------------------------------------------
template <int USE_PART>
__global__ __launch_bounds__(256, 4) void k3_attn(
    const unsigned* __restrict__ pack, const _Float16* __restrict__ whB,
    const float* __restrict__ s_src, const float* __restrict__ s_dst,
    const unsigned* __restrict__ smax_enc,
    float* __restrict__ outp, float* __restrict__ l_ws)
{
    constexpr int STEPS_ = NN / NSPL / 32;   // 16

    const int b      = blockIdx.x;
    const int jsplit = b % NSPL;
    const int r2     = b / NSPL;
    const int hh     = r2 & 3;
    const int grp    = r2 >> 2;
    const int w      = threadIdx.x >> 6;
    const int lane   = threadIdx.x & 63;
    const int row16  = lane & 15;
    const int quad   = lane >> 4;
    const int i0     = (grp * 4 + w) * 32;
    const int jb0    = jsplit * (NN / NSPL);
    const int jblk0  = jb0 >> 5;

    const float sm = dec_f32(smax_enc[hh]);
    float A1[2], A2[2];
    const unsigned* prow[2];
#pragma unroll
    for (int f = 0; f < 2; ++f) {
        const int ir = i0 + f*16 + row16;
        const float s_i = s_src[hh*NN + ir];
        const float zb  = s_i + sm;
        const float mb  = fmaxf(zb, 0.2f * zb);
        A1[f] = s_i - mb;
        A2[f] = 0.2f * s_i - mb;
        prow[f] = pack + ir*128 + jblk0;
    }

    f32x4 acc[2][4];
    f32x4 accl[2];
#pragma unroll
    for (int f = 0; f < 2; ++f) {
        accl[f] = (f32x4){0,0,0,0};
#pragma unroll
        for (int ob = 0; ob < 4; ++ob) acc[f][ob] = (f32x4){0,0,0,0};
    }

    f16x8 ones;
#pragma unroll
    for (int e = 0; e < 8; ++e) ones[e] = (_Float16)1.0f;

    const _Float16* bB  = whB + (size_t)(hh*NGRP + jblk0)*2048 + lane*8;
    const float*    sdp = s_dst + hh*NN + jb0 + quad*8;

    // prologue: step-0 B-frags, masks, s_dst
    f16x8 B0 = *reinterpret_cast<const f16x8*>(bB);
    f16x8 B1 = *reinterpret_cast<const f16x8*>(bB + 512);
    f16x8 B2 = *reinterpret_cast<const f16x8*>(bB + 1024);
    f16x8 B3 = *reinterpret_cast<const f16x8*>(bB + 1536);
    unsigned msk0 = prow[0][0], msk1 = prow[1][0];
    float4 sj0 = *reinterpret_cast<const float4*>(sdp);
    float4 sj1 = *reinterpret_cast<const float4*>(sdp + 4);

    for (int s = 0; s < STEPS_; ++s) {
        // ---- prefetch step s+1 (bounded overread lands in ws, harmless) ----
        const _Float16* bn = bB + (s+1)*2048;
        f16x8 nB0 = *reinterpret_cast<const f16x8*>(bn);
        f16x8 nB1 = *reinterpret_cast<const f16x8*>(bn + 512);
        f16x8 nB2 = *reinterpret_cast<const f16x8*>(bn + 1024);
        f16x8 nB3 = *reinterpret_cast<const f16x8*>(bn + 1536);
        unsigned nmsk0 = prow[0][s+1], nmsk1 = prow[1][s+1];
        float4 nsj0 = *reinterpret_cast<const float4*>(sdp + (s+1)*32);
        float4 nsj1 = *reinterpret_cast<const float4*>(sdp + (s+1)*32 + 4);

        const float sjv[8] = {sj0.x,sj0.y,sj0.z,sj0.w,sj1.x,sj1.y,sj1.z,sj1.w};
        float us[8];
#pragma unroll
        for (int e = 0; e < 8; ++e) us[e] = 0.2f * sjv[e];

        const unsigned mskf[2] = {msk0, msk1};
#pragma unroll
        for (int f = 0; f < 2; ++f) {
            const unsigned mm8 = (mskf[f] >> (quad * 8)) & 0xffu;
            float pe[8];
#pragma unroll
            for (int e = 0; e < 8; ++e) {
                float t1 = A1[f] + sjv[e];
                float t2 = A2[f] + us[e];
                float p  = __builtin_amdgcn_exp2f(fmaxf(t1, t2));
                pe[e] = (mm8 & (1u << e)) ? p : 0.0f;
            }
            union { f16x8 v8; fp16x2 p2[4]; } pa;
#pragma unroll
            for (int e2 = 0; e2 < 4; ++e2)
                pa.p2[e2] = __builtin_amdgcn_cvt_pkrtz(pe[2*e2], pe[2*e2+1]);

            acc[f][0] = __builtin_amdgcn_mfma_f32_16x16x32_f16(pa.v8, B0, acc[f][0], 0, 0, 0);
            acc[f][1] = __builtin_amdgcn_mfma_f32_16x16x32_f16(pa.v8, B1, acc[f][1], 0, 0, 0);
            acc[f][2] = __builtin_amdgcn_mfma_f32_16x16x32_f16(pa.v8, B2, acc[f][2], 0, 0, 0);
            acc[f][3] = __builtin_amdgcn_mfma_f32_16x16x32_f16(pa.v8, B3, acc[f][3], 0, 0, 0);
            accl[f]   = __builtin_amdgcn_mfma_f32_16x16x32_f16(pa.v8, ones, accl[f], 0, 0, 0);
        }

        B0 = nB0; B1 = nB1; B2 = nB2; B3 = nB3;
        msk0 = nmsk0; msk1 = nmsk1;
        sj0 = nsj0; sj1 = nsj1;
    }

    // ---- epilogue ----
#pragma unroll
    for (int f = 0; f < 2; ++f) {
        if (row16 == 0) {
#pragma unroll
            for (int q = 0; q < 4; ++q) {
                const int ir = i0 + f*16 + quad*4 + q;
                if (USE_PART) l_ws[(jsplit*NH + hh)*NN + ir] = accl[f][q];
                else          atomicAdd(&l_ws[hh*NN + ir], accl[f][q]);
            }
        }
    }
    if (USE_PART) {
        // wave-native: part[sp][h][g][f][ob][q][lane] -> 256B coalesced stores
        float* pw = outp + ((size_t)((jsplit*NH + hh)*NGRP + (i0 >> 5))) * 2048 + lane;
#pragma unroll
        for (int f = 0; f < 2; ++f)
#pragma unroll
            for (int ob = 0; ob < 4; ++ob)
#pragma unroll
                for (int q = 0; q < 4; ++q)
                    pw[((f*4 + ob)*4 + q)*64] = acc[f][ob][q];
    } else {
#pragma unroll
        for (int f = 0; f < 2; ++f)
#pragma unroll
            for (int ob = 0; ob < 4; ++ob)
#pragma unroll
                for (int q = 0; q < 4; ++q) {
                    const int grow = i0 + f*16 + quad*4 + q;
                    const int gcol = hh*OUTF + ob*16 + row16;
                    atomicAdd(&outp[(size_t)grow*256 + gcol], acc[f][ob][q]);
                }
    }
}

// ---------------------------------------------------------------------------
// K4 (partials): unscramble wave-native partials, out = sum(part)/sum(l)
// ---------------------------------------------------------------------------
__global__ __launch_bounds__(256) void k4_part(const float* __restrict__ part,
                                               const float* __restrict__ l_ws,
                                               float* __restrict__ out)
{
    const int idx = blockIdx.x * 256 + threadIdx.x;   // f32x4 index, < 262144
    const int n = idx >> 6, c4 = idx & 63;
    const int h = c4 >> 4, k = c4 & 15;
    const int g = n >> 5, f = (n >> 4) & 1, quad = (n >> 2) & 3, q = n & 3;
    const int ob = k >> 2, lb = quad*16 + (k & 3)*4;

    float L = 0.f;
    f32x4 v = {0,0,0,0};
#pragma unroll
    for (int sp = 0; sp < NSPL; ++sp) {
        L += l_ws[(sp*NH + h)*NN + n];
        const float* p = part + ((size_t)((sp*NH + h)*NGRP + g))*2048
                              + ((f*4 + ob)*4 + q)*64 + lb;
        v += *reinterpret_cast<const f32x4*>(p);
    }
    const float inv = 1.0f / L;
    *reinterpret_cast<f32x4*>(out + (size_t)n*256 + c4*4) = v * inv;
}

// K4 (atomic fallback): out /= l
__global__ __launch_bounds__(256) void k4_atomic(float* __restrict__ out,
                                                 const float* __restrict__ l_acc)
{
    const int idx = blockIdx.x * 256 + threadIdx.x;
    const int n = idx >> 6, c4 = idx & 63, h = c4 >> 4;
    const float inv = 1.0f / l_acc[h*NN + n];
    f32x4 v = *reinterpret_cast<f32x4*>(out + (size_t)n*256 + c4*4);
    *reinterpret_cast<f32x4*>(out + (size_t)n*256 + c4*4) = v * inv;
}

extern "C" void kernel_launch(void* const* d_in, const int* in_sizes, int n_in,
                              void* d_out, int out_size, void* d_ws, size_t ws_size,
                              hipStream_t stream)
{
    const float* x   = (const float*)d_in[0];
    const float* adj = (const float*)d_in[1];
    const float* W   = (const float*)d_in[2];
    const float* a   = (const float*)d_in[3];
    float* out = (float*)d_out;

    char* ws = (char*)d_ws;
    _Float16* whB  = (_Float16*)ws;                              // 2 MB
    unsigned* pack = (unsigned*)(ws + (2u<<20));                 // 2 MB
    float* s_src   = (float*)(ws + (4u<<20));                    // 64 KB
    float* s_dst   = (float*)(ws + (4u<<20) + (64u<<10));        // 64 KB
    unsigned* smax = (unsigned*)(ws + (4u<<20) + (128u<<10));    // 1 KB slot
    float* l_ws    = (float*)(ws + (4u<<20) + (129u<<10));       // 512 KB
    float* part    = (float*)(ws + (4u<<20) + (641u<<10));       // 32 MB

    const size_t need = (4u<<20) + (641u<<10) + (size_t)NSPL * NN * 256 * 4;

    k0_pack<<<NN, 256, 0, stream>>>(adj, pack, smax);
    k1_wh  <<<NN/8, 256, 0, stream>>>(x, W, a, whB, s_src, s_dst, smax);

    if (ws_size >= need) {
        k3_attn<1><<<1024, 256, 0, stream>>>(pack, whB, s_src, s_dst, smax, part, l_ws);
        k4_part<<<1024, 256, 0, stream>>>(part, l_ws, out);
    } else {
        (void)hipMemsetAsync(d_out, 0, (size_t)out_size * sizeof(float), stream);
        (void)hipMemsetAsync(l_ws, 0, NH * NN * sizeof(float), stream);
        k3_attn<0><<<1024, 256, 0, stream>>>(pack, whB, s_src, s_dst, smax, out, l_ws);
        k4_atomic<<<1024, 256, 0, stream>>>(out, l_ws);
    }
}

// Round 8
// 81.034 us; speedup vs baseline: 1.9017x; 1.2063x over previous
//
#include <hip/hip_runtime.h>
#include <hip/hip_bf16.h>

typedef float    f32x4 __attribute__((ext_vector_type(4)));
typedef _Float16 f16x8 __attribute__((ext_vector_type(8)));
typedef _Float16 f16x4 __attribute__((ext_vector_type(4)));
typedef __fp16   fp16x2 __attribute__((ext_vector_type(2)));

#define NN 4096
#define INF_ 256
#define OUTF 64
#define NH 4
#define NSPL 8
#define NGRP 128            // NN/32
#define LOG2E 1.4426950408889634f

// ---------------------------------------------------------------------------
// K0: pack adj (0/1 floats) into bitmask; diagonal forced 1; init smax.
// ---------------------------------------------------------------------------
__global__ __launch_bounds__(256) void k0_pack(const float* __restrict__ adj,
                                               unsigned* __restrict__ pack,
                                               unsigned* __restrict__ smax)
{
    const int r    = blockIdx.x;
    const int w    = threadIdx.x >> 6;
    const int lane = threadIdx.x & 63;
    const float* row = adj + (size_t)r * NN + w * 1024;
#pragma unroll
    for (int i = 0; i < 4; ++i) {
        float a0 = row[i*256 + lane];
        float a1 = row[i*256 +  64 + lane];
        float a2 = row[i*256 + 128 + lane];
        float a3 = row[i*256 + 192 + lane];
        unsigned long long bal[4];
        bal[0] = __ballot(a0 != 0.f);
        bal[1] = __ballot(a1 != 0.f);
        bal[2] = __ballot(a2 != 0.f);
        bal[3] = __ballot(a3 != 0.f);
        if (lane < 2) {
#pragma unroll
            for (int k = 0; k < 4; ++k) {
                int wi = w*32 + i*8 + k*2 + lane;
                unsigned v = (unsigned)(bal[k] >> (lane * 32));
                if (wi == (r >> 5)) v |= 1u << (r & 31);   // diagonal
                pack[r*128 + wi] = v;
            }
        }
    }
    if (r == 0 && threadIdx.x < NH) smax[threadIdx.x] = 0u;
}

__device__ __forceinline__ unsigned enc_f32(float f) {
    unsigned u = __float_as_uint(f);
    return (u & 0x80000000u) ? ~u : (u | 0x80000000u);
}
__device__ __forceinline__ float dec_f32(unsigned u) {
    return (u & 0x80000000u) ? __uint_as_float(u ^ 0x80000000u)
                             : __uint_as_float(~u);
}

// ---------------------------------------------------------------------------
// KW: transpose W into MFMA-B fragment-native f16, split hi/lo:
// wB{h,l}[h][ks][ob][lane][e] = f16split(W[h][ks*32+quad*8+e][ob*16+row16]).
// Grid 32 blocks = (h, kstep); 256 threads = (ob, lane).
// ---------------------------------------------------------------------------
__global__ __launch_bounds__(256) void kW_tr(const float* __restrict__ W,
                                             _Float16* __restrict__ wBh,
                                             _Float16* __restrict__ wBl)
{
    const int b = blockIdx.x;
    const int h = b >> 3, ks = b & 7;
    const int t = threadIdx.x;
    const int ob = t >> 6, lane = t & 63;
    const int row16 = lane & 15, quad = lane >> 4;

    const float* wp = W + (size_t)h*INF_*OUTF + (ks*32 + quad*8)*OUTF + ob*16 + row16;
    f16x8 vh, vl;
#pragma unroll
    for (int e = 0; e < 8; ++e) {
        float v = wp[e*OUTF];
        _Float16 hi = (_Float16)v;
        vh[e] = hi;
        vl[e] = (_Float16)(v - (float)hi);
    }
    const int idx = ((h*8 + ks)*4 + ob)*64 + lane;
    reinterpret_cast<f16x8*>(wBh)[idx] = vh;
    reinterpret_cast<f16x8*>(wBl)[idx] = vl;
}

// ---------------------------------------------------------------------------
// K1m: Wh = x @ W via MFMA with 3-term double-f16 split (f32-accurate).
// Grid 256 = (h, 64-row group); 4 waves x 16 rows. Per wave: 8 k-steps x
// {A-load 32B + split + 4 ob x 3 MFMAs}. Epilogue: s_src/s_dst (f32
// shfl-reduce), smax atomicMax, whB fragment-native store.
// ---------------------------------------------------------------------------
__global__ __launch_bounds__(256) void k1m(
    const float* __restrict__ x, const _Float16* __restrict__ wBh,
    const _Float16* __restrict__ wBl, const float* __restrict__ a,
    _Float16* __restrict__ whB, float* __restrict__ s_src,
    float* __restrict__ s_dst, unsigned* __restrict__ smax)
{
    const int b = blockIdx.x;
    const int h = b >> 6, rb = b & 63;
    const int w = threadIdx.x >> 6, lane = threadIdx.x & 63;
    const int row16 = lane & 15, quad = lane >> 4;
    const int n0 = rb*64 + w*16;

    f32x4 acc[4];
#pragma unroll
    for (int ob = 0; ob < 4; ++ob) acc[ob] = (f32x4){0,0,0,0};

    const float* xp = x + (size_t)(n0 + row16)*INF_ + quad*8;
    const f16x8* WH = reinterpret_cast<const f16x8*>(wBh) + (h*8*4)*64 + lane;
    const f16x8* WL = reinterpret_cast<const f16x8*>(wBl) + (h*8*4)*64 + lane;

#pragma unroll
    for (int ks = 0; ks < 8; ++ks) {
        float4 xv0 = *reinterpret_cast<const float4*>(xp + ks*32);
        float4 xv1 = *reinterpret_cast<const float4*>(xp + ks*32 + 4);
        const float xv[8] = {xv0.x,xv0.y,xv0.z,xv0.w,xv1.x,xv1.y,xv1.z,xv1.w};
        f16x8 Ah, Al;
#pragma unroll
        for (int e = 0; e < 8; ++e) {
            _Float16 hi = (_Float16)xv[e];
            Ah[e] = hi;
            Al[e] = (_Float16)(xv[e] - (float)hi);
        }
#pragma unroll
        for (int ob = 0; ob < 4; ++ob) {
            f16x8 bh = WH[(ks*4 + ob)*64];
            f16x8 bl = WL[(ks*4 + ob)*64];
            acc[ob] = __builtin_amdgcn_mfma_f32_16x16x32_f16(Ah, bh, acc[ob], 0, 0, 0);
            acc[ob] = __builtin_amdgcn_mfma_f32_16x16x32_f16(Al, bh, acc[ob], 0, 0, 0);
            acc[ob] = __builtin_amdgcn_mfma_f32_16x16x32_f16(Ah, bl, acc[ob], 0, 0, 0);
        }
    }

    // ---- whB fragment-native store: 8B per ob ----
    {
        const int jblk = n0 >> 5;
        const int qb   = ((n0 & 16) >> 3) + (quad >> 1);
        const int e0   = (quad & 1) * 4;
#pragma unroll
        for (int ob = 0; ob < 4; ++ob) {
            f16x4 st;
#pragma unroll
            for (int q = 0; q < 4; ++q) st[q] = (_Float16)acc[ob][q];
            const size_t off = (((size_t)(h*NGRP + jblk)*4 + ob)*64 + qb*16 + row16)*8 + e0;
            *reinterpret_cast<f16x4*>(whB + off) = st;
        }
    }

    // ---- s_src/s_dst/smax ----
    float asv[4], adv[4];
#pragma unroll
    for (int ob = 0; ob < 4; ++ob) {
        asv[ob] = a[h*128 + ob*16 + row16];
        adv[ob] = a[h*128 + 64 + ob*16 + row16];
    }
    float sq_s[4], sq_d[4];
#pragma unroll
    for (int q = 0; q < 4; ++q) {
        float vs = 0.f, vd = 0.f;
#pragma unroll
        for (int ob = 0; ob < 4; ++ob) {
            vs += acc[ob][q] * asv[ob];
            vd += acc[ob][q] * adv[ob];
        }
#pragma unroll
        for (int m = 1; m <= 8; m <<= 1) {
            vs += __shfl_xor(vs, m);
            vd += __shfl_xor(vd, m);
        }
        sq_s[q] = vs; sq_d[q] = vd;
    }
    if (row16 == 0) {
        float vmax = -3.0e38f;
#pragma unroll
        for (int q = 0; q < 4; ++q) {
            const int n = n0 + quad*4 + q;
            s_src[h*NN + n] = LOG2E * sq_s[q];
            const float sd = LOG2E * sq_d[q];
            s_dst[h*NN + n] = sd;
            vmax = fmaxf(vmax, sd);
        }
        atomicMax(&smax[h], enc_f32(vmax));
    }
}

// ---------------------------------------------------------------------------
// K3: barrier-free fused softmax + P@Wh (unchanged from round 7).
// ---------------------------------------------------------------------------
template <int USE_PART>
__global__ __launch_bounds__(256, 4) void k3_attn(
    const unsigned* __restrict__ pack, const _Float16* __restrict__ whB,
    const float* __restrict__ s_src, const float* __restrict__ s_dst,
    const unsigned* __restrict__ smax_enc,
    float* __restrict__ outp, float* __restrict__ l_ws)
{
    constexpr int STEPS_ = NN / NSPL / 32;   // 16

    const int b      = blockIdx.x;
    const int jsplit = b % NSPL;
    const int r2     = b / NSPL;
    const int hh     = r2 & 3;
    const int grp    = r2 >> 2;
    const int w      = threadIdx.x >> 6;
    const int lane   = threadIdx.x & 63;
    const int row16  = lane & 15;
    const int quad   = lane >> 4;
    const int i0     = (grp * 4 + w) * 32;
    const int jb0    = jsplit * (NN / NSPL);
    const int jblk0  = jb0 >> 5;

    const float sm = dec_f32(smax_enc[hh]);
    float A1[2], A2[2];
    const unsigned* prow[2];
#pragma unroll
    for (int f = 0; f < 2; ++f) {
        const int ir = i0 + f*16 + row16;
        const float s_i = s_src[hh*NN + ir];
        const float zb  = s_i + sm;
        const float mb  = fmaxf(zb, 0.2f * zb);
        A1[f] = s_i - mb;
        A2[f] = 0.2f * s_i - mb;
        prow[f] = pack + ir*128 + jblk0;
    }

    f32x4 acc[2][4];
    f32x4 accl[2];
#pragma unroll
    for (int f = 0; f < 2; ++f) {
        accl[f] = (f32x4){0,0,0,0};
#pragma unroll
        for (int ob = 0; ob < 4; ++ob) acc[f][ob] = (f32x4){0,0,0,0};
    }

    f16x8 ones;
#pragma unroll
    for (int e = 0; e < 8; ++e) ones[e] = (_Float16)1.0f;

    const _Float16* bB  = whB + (size_t)(hh*NGRP + jblk0)*2048 + lane*8;
    const float*    sdp = s_dst + hh*NN + jb0 + quad*8;

    f16x8 B0 = *reinterpret_cast<const f16x8*>(bB);
    f16x8 B1 = *reinterpret_cast<const f16x8*>(bB + 512);
    f16x8 B2 = *reinterpret_cast<const f16x8*>(bB + 1024);
    f16x8 B3 = *reinterpret_cast<const f16x8*>(bB + 1536);
    unsigned msk0 = prow[0][0], msk1 = prow[1][0];
    float4 sj0 = *reinterpret_cast<const float4*>(sdp);
    float4 sj1 = *reinterpret_cast<const float4*>(sdp + 4);

    for (int s = 0; s < STEPS_; ++s) {
        const _Float16* bn = bB + (s+1)*2048;
        f16x8 nB0 = *reinterpret_cast<const f16x8*>(bn);
        f16x8 nB1 = *reinterpret_cast<const f16x8*>(bn + 512);
        f16x8 nB2 = *reinterpret_cast<const f16x8*>(bn + 1024);
        f16x8 nB3 = *reinterpret_cast<const f16x8*>(bn + 1536);
        unsigned nmsk0 = prow[0][s+1], nmsk1 = prow[1][s+1];
        float4 nsj0 = *reinterpret_cast<const float4*>(sdp + (s+1)*32);
        float4 nsj1 = *reinterpret_cast<const float4*>(sdp + (s+1)*32 + 4);

        const float sjv[8] = {sj0.x,sj0.y,sj0.z,sj0.w,sj1.x,sj1.y,sj1.z,sj1.w};
        float us[8];
#pragma unroll
        for (int e = 0; e < 8; ++e) us[e] = 0.2f * sjv[e];

        const unsigned mskf[2] = {msk0, msk1};
#pragma unroll
        for (int f = 0; f < 2; ++f) {
            const unsigned mm8 = (mskf[f] >> (quad * 8)) & 0xffu;
            float pe[8];
#pragma unroll
            for (int e = 0; e < 8; ++e) {
                float t1 = A1[f] + sjv[e];
                float t2 = A2[f] + us[e];
                float p  = __builtin_amdgcn_exp2f(fmaxf(t1, t2));
                pe[e] = (mm8 & (1u << e)) ? p : 0.0f;
            }
            union { f16x8 v8; fp16x2 p2[4]; } pa;
#pragma unroll
            for (int e2 = 0; e2 < 4; ++e2)
                pa.p2[e2] = __builtin_amdgcn_cvt_pkrtz(pe[2*e2], pe[2*e2+1]);

            acc[f][0] = __builtin_amdgcn_mfma_f32_16x16x32_f16(pa.v8, B0, acc[f][0], 0, 0, 0);
            acc[f][1] = __builtin_amdgcn_mfma_f32_16x16x32_f16(pa.v8, B1, acc[f][1], 0, 0, 0);
            acc[f][2] = __builtin_amdgcn_mfma_f32_16x16x32_f16(pa.v8, B2, acc[f][2], 0, 0, 0);
            acc[f][3] = __builtin_amdgcn_mfma_f32_16x16x32_f16(pa.v8, B3, acc[f][3], 0, 0, 0);
            accl[f]   = __builtin_amdgcn_mfma_f32_16x16x32_f16(pa.v8, ones, accl[f], 0, 0, 0);
        }

        B0 = nB0; B1 = nB1; B2 = nB2; B3 = nB3;
        msk0 = nmsk0; msk1 = nmsk1;
        sj0 = nsj0; sj1 = nsj1;
    }

#pragma unroll
    for (int f = 0; f < 2; ++f) {
        if (row16 == 0) {
#pragma unroll
            for (int q = 0; q < 4; ++q) {
                const int ir = i0 + f*16 + quad*4 + q;
                if (USE_PART) l_ws[(jsplit*NH + hh)*NN + ir] = accl[f][q];
                else          atomicAdd(&l_ws[hh*NN + ir], accl[f][q]);
            }
        }
    }
    if (USE_PART) {
        float* pw = outp + ((size_t)((jsplit*NH + hh)*NGRP + (i0 >> 5))) * 2048 + lane;
#pragma unroll
        for (int f = 0; f < 2; ++f)
#pragma unroll
            for (int ob = 0; ob < 4; ++ob)
#pragma unroll
                for (int q = 0; q < 4; ++q)
                    pw[((f*4 + ob)*4 + q)*64] = acc[f][ob][q];
    } else {
#pragma unroll
        for (int f = 0; f < 2; ++f)
#pragma unroll
            for (int ob = 0; ob < 4; ++ob)
#pragma unroll
                for (int q = 0; q < 4; ++q) {
                    const int grow = i0 + f*16 + quad*4 + q;
                    const int gcol = hh*OUTF + ob*16 + row16;
                    atomicAdd(&outp[(size_t)grow*256 + gcol], acc[f][ob][q]);
                }
    }
}

// ---------------------------------------------------------------------------
// K4 (partials): unscramble wave-native partials, out = sum(part)/sum(l)
// ---------------------------------------------------------------------------
__global__ __launch_bounds__(256) void k4_part(const float* __restrict__ part,
                                               const float* __restrict__ l_ws,
                                               float* __restrict__ out)
{
    const int idx = blockIdx.x * 256 + threadIdx.x;
    const int n = idx >> 6, c4 = idx & 63;
    const int h = c4 >> 4, k = c4 & 15;
    const int g = n >> 5, f = (n >> 4) & 1, quad = (n >> 2) & 3, q = n & 3;
    const int ob = k >> 2, lb = quad*16 + (k & 3)*4;

    float L = 0.f;
    f32x4 v = {0,0,0,0};
#pragma unroll
    for (int sp = 0; sp < NSPL; ++sp) {
        L += l_ws[(sp*NH + h)*NN + n];
        const float* p = part + ((size_t)((sp*NH + h)*NGRP + g))*2048
                              + ((f*4 + ob)*4 + q)*64 + lb;
        v += *reinterpret_cast<const f32x4*>(p);
    }
    const float inv = 1.0f / L;
    *reinterpret_cast<f32x4*>(out + (size_t)n*256 + c4*4) = v * inv;
}

// K4 (atomic fallback): out /= l
__global__ __launch_bounds__(256) void k4_atomic(float* __restrict__ out,
                                                 const float* __restrict__ l_acc)
{
    const int idx = blockIdx.x * 256 + threadIdx.x;
    const int n = idx >> 6, c4 = idx & 63, h = c4 >> 4;
    const float inv = 1.0f / l_acc[h*NN + n];
    f32x4 v = *reinterpret_cast<f32x4*>(out + (size_t)n*256 + c4*4);
    *reinterpret_cast<f32x4*>(out + (size_t)n*256 + c4*4) = v * inv;
}

extern "C" void kernel_launch(void* const* d_in, const int* in_sizes, int n_in,
                              void* d_out, int out_size, void* d_ws, size_t ws_size,
                              hipStream_t stream)
{
    const float* x   = (const float*)d_in[0];
    const float* adj = (const float*)d_in[1];
    const float* W   = (const float*)d_in[2];
    const float* a   = (const float*)d_in[3];
    float* out = (float*)d_out;

    char* ws = (char*)d_ws;
    _Float16* whB  = (_Float16*)ws;                              // 2 MB
    unsigned* pack = (unsigned*)(ws + (2u<<20));                 // 2 MB
    _Float16* wBh  = (_Float16*)(ws + (4u<<20));                 // 128 KB
    _Float16* wBl  = (_Float16*)(ws + (4u<<20) + (128u<<10));    // 128 KB
    float* s_src   = (float*)(ws + (4u<<20) + (256u<<10));       // 64 KB
    float* s_dst   = (float*)(ws + (4u<<20) + (320u<<10));       // 64 KB
    unsigned* smax = (unsigned*)(ws + (4u<<20) + (384u<<10));    // 1 KB slot
    float* l_ws    = (float*)(ws + (4u<<20) + (385u<<10));       // 512 KB
    float* part    = (float*)(ws + (4u<<20) + (897u<<10));       // 32 MB

    const size_t need = (4u<<20) + (897u<<10) + (size_t)NSPL * NN * 256 * 4;

    k0_pack<<<NN, 256, 0, stream>>>(adj, pack, smax);
    kW_tr  <<<32, 256, 0, stream>>>(W, wBh, wBl);
    k1m    <<<256, 256, 0, stream>>>(x, wBh, wBl, a, whB, s_src, s_dst, smax);

    if (ws_size >= need) {
        k3_attn<1><<<1024, 256, 0, stream>>>(pack, whB, s_src, s_dst, smax, part, l_ws);
        k4_part<<<1024, 256, 0, stream>>>(part, l_ws, out);
    } else {
        (void)hipMemsetAsync(d_out, 0, (size_t)out_size * sizeof(float), stream);
        (void)hipMemsetAsync(l_ws, 0, NH * NN * sizeof(float), stream);
        k3_attn<0><<<1024, 256, 0, stream>>>(pack, whB, s_src, s_dst, smax, out, l_ws);
        k4_atomic<<<1024, 256, 0, stream>>>(out, l_ws);
    }
}